// Round 5
// baseline (5491.009 us; speedup 1.0000x reference)
//
#include <hip/hip_runtime.h>
#include <stdint.h>

typedef __bf16 bf16_t;
typedef __bf16 bf16x8 __attribute__((ext_vector_type(8)));
typedef __bf16 bf16x4 __attribute__((ext_vector_type(4)));
typedef float f32x4 __attribute__((ext_vector_type(4)));
typedef unsigned short ushort_t;

#define CC 768
#define HD 3072
#define TB 196
#define HWD 14
#define EPSF 1e-5f
#define INV_T (1.0f/196.0f)

// ---------------- helpers ----------------
__device__ __forceinline__ float wave_sum(float v) {
#pragma unroll
  for (int off = 32; off > 0; off >>= 1) v += __shfl_xor(v, off, 64);
  return v;
}

__device__ __forceinline__ void async_copy16(const void* g, void* l) {
  typedef __attribute__((address_space(3))) uint32_t lds_u32;
  typedef __attribute__((address_space(1))) const uint32_t glb_u32;
  glb_u32* gp = (glb_u32*)(uintptr_t)g;
  lds_u32* lp = (lds_u32*)(uint32_t)(uintptr_t)l;
  __builtin_amdgcn_global_load_lds(gp, lp, 16, 0, 0);
}

#define SCHED_FENCE() asm volatile("" ::: "memory")
#define BAR() asm volatile("s_barrier" ::: "memory")
#define LGKM0() asm volatile("s_waitcnt lgkmcnt(0)" ::: "memory")

// ---------------- LN0 (normalized row to XB + stats of output row) ----------------
__global__ __launch_bounds__(256) void k_ln0(const float* __restrict__ in,
                                             const float* __restrict__ g,
                                             const float* __restrict__ b,
                                             float* __restrict__ out,
                                             float* __restrict__ st, int M) {
  int row = blockIdx.x * 4 + (threadIdx.x >> 6);
  if (row >= M) return;
  int lane = threadIdx.x & 63;
  const float* rp = in + (size_t)row * CC;
  int c0 = lane * 4;
  f32x4 x[3];
#pragma unroll
  for (int s = 0; s < 3; ++s) x[s] = *(const f32x4*)(rp + s * 256 + c0);
  float sum = 0.f;
#pragma unroll
  for (int s = 0; s < 3; ++s)
#pragma unroll
    for (int j = 0; j < 4; ++j) sum += x[s][j];
  float mean = wave_sum(sum) * (1.0f / CC);
  float s2 = 0.f;
#pragma unroll
  for (int s = 0; s < 3; ++s)
#pragma unroll
    for (int j = 0; j < 4; ++j) { float d = x[s][j] - mean; s2 += d * d; }
  float rs = rsqrtf(wave_sum(s2) * (1.0f / CC) + EPSF);
  float* op = out + (size_t)row * CC;
  f32x4 o[3];
  float sum2 = 0.f;
#pragma unroll
  for (int s = 0; s < 3; ++s) {
    int cc = s * 256 + c0;
    f32x4 gg = *(const f32x4*)(g + cc);
    f32x4 bb = *(const f32x4*)(b + cc);
#pragma unroll
    for (int j = 0; j < 4; ++j) {
      o[s][j] = (x[s][j] - mean) * rs * gg[j] + bb[j];
      sum2 += o[s][j];
    }
    *(f32x4*)(op + cc) = o[s];
  }
  float mean2 = wave_sum(sum2) * (1.0f / CC);
  float q2 = 0.f;
#pragma unroll
  for (int s = 0; s < 3; ++s)
#pragma unroll
    for (int j = 0; j < 4; ++j) { float d = o[s][j] - mean2; q2 += d * d; }
  float rs2 = rsqrtf(wave_sum(q2) * (1.0f / CC) + EPSF);
  if (lane == 0) { st[2 * row] = mean2; st[2 * row + 1] = rs2; }
}

// ---------------- per-row mean/rstd ----------------
__global__ __launch_bounds__(256) void k_stats(const float* __restrict__ in,
                                               float* __restrict__ st, int M) {
  int row = blockIdx.x * 4 + (threadIdx.x >> 6);
  if (row >= M) return;
  int lane = threadIdx.x & 63;
  const float* rp = in + (size_t)row * CC;
  int c0 = lane * 4;
  f32x4 x[3];
#pragma unroll
  for (int s = 0; s < 3; ++s) x[s] = *(const f32x4*)(rp + s * 256 + c0);
  float sum = 0.f;
#pragma unroll
  for (int s = 0; s < 3; ++s)
#pragma unroll
    for (int j = 0; j < 4; ++j) sum += x[s][j];
  float mean = wave_sum(sum) * (1.0f / CC);
  float s2 = 0.f;
#pragma unroll
  for (int s = 0; s < 3; ++s)
#pragma unroll
    for (int j = 0; j < 4; ++j) { float d = x[s][j] - mean; s2 += d * d; }
  float rs = rsqrtf(wave_sum(s2) * (1.0f / CC) + EPSF);
  if (lane == 0) { st[2 * row] = mean; st[2 * row + 1] = rs; }
}

// ---------------- LN + q_shift + token-mix, bf16 outputs ----------------
template <int NOUT>
__global__ __launch_bounds__(256) void k_mix(const float* __restrict__ xb,
                                             const float* __restrict__ st,
                                             const float* __restrict__ g,
                                             const float* __restrict__ b,
                                             const float* __restrict__ mk,
                                             const float* __restrict__ mv,
                                             const float* __restrict__ mr,
                                             bf16_t* __restrict__ ok,
                                             bf16_t* __restrict__ ov,
                                             bf16_t* __restrict__ orr, int M) {
  int tok = blockIdx.x * 4 + (threadIdx.x >> 6);
  if (tok >= M) return;
  int lane = threadIdx.x & 63;
  int t = tok % TB;
  int h = t / HWD, w = t % HWD;
  int nbr[4];
  nbr[0] = (w > 0)       ? tok - 1   : -1;
  nbr[1] = (w < HWD - 1) ? tok + 1   : -1;
  nbr[2] = (h > 0)       ? tok - HWD : -1;
  nbr[3] = (h < HWD - 1) ? tok + HWD : -1;
  float ms = st[2 * tok], rss = st[2 * tok + 1];
  const float* rp = xb + (size_t)tok * CC;
#pragma unroll
  for (int s = 0; s < 3; ++s) {
    int cc = s * 256 + lane * 4;
    int grp = cc / 192;
    int nb = nbr[grp];
    f32x4 xs = *(const f32x4*)(rp + cc);
    f32x4 xn = {0.f, 0.f, 0.f, 0.f};
    float mn = 0.f, rsn = 0.f;
    if (nb >= 0) {
      xn = *(const f32x4*)(xb + (size_t)nb * CC + cc);
      mn = st[2 * nb];
      rsn = st[2 * nb + 1];
    }
    f32x4 gg = *(const f32x4*)(g + cc);
    f32x4 bb = *(const f32x4*)(b + cc);
    f32x4 mk4 = *(const f32x4*)(mk + cc);
    f32x4 mr4 = *(const f32x4*)(mr + cc);
    f32x4 mv4 = {0.f, 0.f, 0.f, 0.f};
    if (NOUT == 3) mv4 = *(const f32x4*)(mv + cc);
    bf16x4 vk, vv, vr;
#pragma unroll
    for (int j = 0; j < 4; ++j) {
      float xi = (xs[j] - ms) * rss * gg[j] + bb[j];
      float xx = (nb >= 0) ? ((xn[j] - mn) * rsn * gg[j] + bb[j]) : 0.f;
      vk[j] = (bf16_t)(xi * mk4[j] + xx * (1.0f - mk4[j]));
      if (NOUT == 3) vv[j] = (bf16_t)(xi * mv4[j] + xx * (1.0f - mv4[j]));
      vr[j] = (bf16_t)(xi * mr4[j] + xx * (1.0f - mr4[j]));
    }
    *(bf16x4*)(ok + (size_t)tok * CC + cc) = vk;
    if (NOUT == 3) *(bf16x4*)(ov + (size_t)tok * CC + cc) = vv;
    *(bf16x4*)(orr + (size_t)tok * CC + cc) = vr;
  }
}

// ---------------- weight f32 (K,N) -> bf16 transposed (N,K) ----------------
__global__ __launch_bounds__(256) void k_tcvt(const float* __restrict__ src,
                                              bf16_t* __restrict__ dst, int K, int N) {
  __shared__ float tile[32][33];
  int tx = threadIdx.x & 31;
  int ty = threadIdx.x >> 5;
  int n0 = blockIdx.x * 32, k0 = blockIdx.y * 32;
#pragma unroll
  for (int i = 0; i < 4; ++i)
    tile[ty + 8 * i][tx] = src[(size_t)(k0 + ty + 8 * i) * N + n0 + tx];
  __syncthreads();
#pragma unroll
  for (int i = 0; i < 4; ++i)
    dst[(size_t)(n0 + ty + 8 * i) * K + k0 + tx] = (bf16_t)tile[tx][ty + 8 * i];
}

// ---------------- MFMA GEMM: 128x128, BK=64, single-buffered A+B, 5 blocks/CU ----------------
// Round-4 decomposition: per-block schedule keeps the matrix pipe only ~7% busy
// (latency/sync-bound); chip MfmaUtil ~= 7% x blocks/CU, and makespan is
// rounds x T_round with rounds = ceil(blocks / (256 x blocks_per_CU)).
// Both losses shrink with co-residency -> this version single-buffers BOTH
// A and B: LDS = 32 KiB exactly -> 160/32 = 5 blocks/CU (20 waves, VGPR cap
// 512/5 = 102 >= 84, no spill). Schedule delta vs round 4 is only that
// stageA joins stageB after the mid-tile barrier (read-before-overwrite).
// Per K-tile: {read A+B frags | lgkm0 | BAR | stage A+B (t+1) | MFMA |
// vmcnt(0) | BAR} - same 2 barriers / 1 lgkm / 1 vmcnt as round 4.
// Exposed per-block load latency rises ~300cy/tile; 5-way block interleave
// on each CU covers it (TLP, not ILP).
enum { EPI_F32 = 0, EPI_SIG_BF16 = 1, EPI_RELU2_BF16 = 2, EPI_ADD = 3, EPI_GATE = 4 };

struct GemmArgs {
  const bf16_t* A;
  const bf16_t* B;
  void* C;
  const bf16_t* gate;   // EPI_GATE
  const float* resid;   // EPI_GATE
  int epi;
  int NT;               // N = NT*128; per-arg so independent gemms fuse in one launch
};
struct GemmBatch { GemmArgs a[3]; };

__global__ __launch_bounds__(256, 5) void k_gemm(GemmBatch batch, int M, int K, int Mt) {
  __shared__ __align__(16) ushort_t sA[128 * 64];
  __shared__ __align__(16) ushort_t sB[128 * 64];
  int p = blockIdx.x, zi = 0;
  int nbk = Mt * batch.a[0].NT;
  while (p >= nbk && zi < 2) { p -= nbk; ++zi; nbk = Mt * batch.a[zi].NT; }
  GemmArgs ga = batch.a[zi];
  int NT = ga.NT;
  int N = NT << 7;
  int G = NT * 8, Mt8 = Mt & ~7;
  int m, n;
  if (p < Mt8 * NT) {
    int g = p / G;
    int r = p - g * G;
    m = g * 8 + (r & 7);
    n = r >> 3;
  } else {
    int r2 = p - Mt8 * NT;
    int rem = Mt - Mt8;
    m = Mt8 + r2 % rem;
    n = r2 / rem;
  }
  int bm = m << 7, bn = n << 7;
  int tid = threadIdx.x;
  int wave = tid >> 6, lane = tid & 63;
  int fr = lane & 15, fq = lane >> 4, fr7 = fr & 7;
  int wm = (wave >> 1) * 64, wn = (wave & 1) * 64;
  int r0 = tid >> 3;          // 0..31: base row for staging
  int pos = tid & 7;          // 16B chunk slot within the 128B LDS row
  int cs = pos ^ (r0 & 7);    // pre-swizzled source chunk ((r0+32j)&7 == r0&7)
  const bf16_t* Ab = ga.A + (size_t)bm * K;
  const bf16_t* Bb = ga.B + (size_t)bn * K;

  auto stageA = [&](int kt) {
    int koff = kt * 64 + cs * 8;
#pragma unroll
    for (int j = 0; j < 4; ++j) {
      int row = j * 32 + r0;
      async_copy16(Ab + (size_t)row * K + koff, &sA[row * 64 + pos * 8]);
    }
  };
  auto stageB = [&](int kt) {
    int koff = kt * 64 + cs * 8;
#pragma unroll
    for (int j = 0; j < 4; ++j) {
      int row = j * 32 + r0;
      async_copy16(Bb + (size_t)row * K + koff, &sB[row * 64 + pos * 8]);
    }
  };

  f32x4 acc[4][4] = {};
  int niter = K >> 6;
  stageA(0);
  stageB(0);
  SCHED_FENCE();
  asm volatile("s_waitcnt vmcnt(0)" ::: "memory");
  BAR();
  for (int t = 0; t < niter; ++t) {
    // sA/sB hold tile t (landed; all waves past the tail BAR of prev iter).
    bf16x8 af[4][2], bfv[4][2];
#pragma unroll
    for (int i = 0; i < 4; ++i) {
      int ra = wm + i * 16 + fr;
      int rb = wn + i * 16 + fr;
#pragma unroll
      for (int ks = 0; ks < 2; ++ks) {
        af[i][ks]  = *(const bf16x8*)&sA[ra * 64 + (((ks * 4 + fq) ^ fr7) << 3)];
        bfv[i][ks] = *(const bf16x8*)&sB[rb * 64 + (((ks * 4 + fq) ^ fr7) << 3)];
      }
    }
    LGKM0();            // own frag reads done
    BAR();              // ALL waves' reads done -> LDS safe to overwrite
    if (t + 1 < niter) { stageA(t + 1); stageB(t + 1); }
    SCHED_FENCE();
    __builtin_amdgcn_s_setprio(1);
#pragma unroll
    for (int ks = 0; ks < 2; ++ks)
#pragma unroll
      for (int mi = 0; mi < 4; ++mi)
#pragma unroll
        for (int ni = 0; ni < 4; ++ni)
          acc[mi][ni] = __builtin_amdgcn_mfma_f32_16x16x32_bf16(af[mi][ks], bfv[ni][ks], acc[mi][ni], 0, 0, 0);
    __builtin_amdgcn_s_setprio(0);
    asm volatile("s_waitcnt vmcnt(0)" ::: "memory");  // tile t+1 landed
    BAR();
  }
  int epi = ga.epi;
#pragma unroll
  for (int mi = 0; mi < 4; ++mi) {
#pragma unroll
    for (int ni = 0; ni < 4; ++ni) {
#pragma unroll
      for (int r = 0; r < 4; ++r) {
        int grow = bm + wm + mi * 16 + fq * 4 + r;
        int gcol = bn + wn + ni * 16 + fr;
        size_t idx = (size_t)grow * N + gcol;
        float v = acc[mi][ni][r];
        if (epi == EPI_F32) {
          ((float*)ga.C)[idx] = v;
        } else if (epi == EPI_SIG_BF16) {
          ((bf16_t*)ga.C)[idx] = (bf16_t)(1.0f / (1.0f + __expf(-v)));
        } else if (epi == EPI_RELU2_BF16) {
          float tv = v > 0.f ? v : 0.f;
          ((bf16_t*)ga.C)[idx] = (bf16_t)(tv * tv);
        } else if (epi == EPI_ADD) {
          ((float*)ga.C)[idx] += v;
        } else {  // EPI_GATE: out = resid + sigmoid-gate * v
          ((float*)ga.C)[idx] = ga.resid[idx] + (float)ga.gate[idx] * v;
        }
      }
    }
  }
}

// ---------------- bidirectional WKV scans ----------------
__global__ __launch_bounds__(256) void k_wkv_bwd(const float* __restrict__ k,
                                                 const float* __restrict__ v,
                                                 const float* __restrict__ decay,
                                                 bf16_t* __restrict__ ba,
                                                 bf16_t* __restrict__ bb, int CB) {
  int idx = blockIdx.x * 256 + threadIdx.x;
  if (idx >= CB * CC) return;
  int c = idx % CC;
  size_t base = (size_t)(idx / CC) * TB * CC + c;
  float w = decay[c] * INV_T;
  float d = __expf(-w);
  float a = 0.f, bs = 0.f;
  for (int t = TB - 1; t >= 0; --t) {
    size_t p = base + (size_t)t * CC;
    ba[p] = (bf16_t)a;
    bb[p] = (bf16_t)bs;
    float ek = __expf(k[p]);
    a = d * (a + ek * v[p]);
    bs = d * (bs + ek);
  }
}

__global__ __launch_bounds__(256) void k_wkv_fwd(const float* __restrict__ k,
                                                 const float* __restrict__ v,
                                                 const float* __restrict__ decay,
                                                 const float* __restrict__ first,
                                                 const bf16_t* __restrict__ ba,
                                                 const bf16_t* __restrict__ bb,
                                                 bf16_t* __restrict__ r, int CB) {
  int idx = blockIdx.x * 256 + threadIdx.x;
  if (idx >= CB * CC) return;
  int c = idx % CC;
  size_t base = (size_t)(idx / CC) * TB * CC + c;
  float w = decay[c] * INV_T;
  float d = __expf(-w);
  float ew = __expf(w);
  float u = first[c] * INV_T;
  float a = 0.f, bs = 0.f;
  for (int t = 0; t < TB; ++t) {
    size_t p = base + (size_t)t * CC;
    float kk = k[p], vv = v[p];
    float eu = __expf(u + kk);
    float num = ew * (a + (float)ba[p]) + eu * vv;
    float den = ew * (bs + (float)bb[p]) + eu;
    r[p] = (bf16_t)(num / den);
    float ek = __expf(kk);
    a = d * (a + ek * vv);
    bs = d * (bs + ek);
  }
}

// ---------------- LN(rwkv bf16) * sr -> bf16 ----------------
__global__ __launch_bounds__(256) void k_ln_mul(const bf16_t* __restrict__ in,
                                                const bf16_t* __restrict__ sr,
                                                const float* __restrict__ g,
                                                const float* __restrict__ b,
                                                bf16_t* __restrict__ out, int M) {
  int row = blockIdx.x * 4 + (threadIdx.x >> 6);
  if (row >= M) return;
  int lane = threadIdx.x & 63;
  const bf16_t* rp = in + (size_t)row * CC;
  int c0 = lane * 4;
  float x[12];
#pragma unroll
  for (int s = 0; s < 3; ++s) {
    bf16x4 t = *(const bf16x4*)(rp + s * 256 + c0);
#pragma unroll
    for (int j = 0; j < 4; ++j) x[s * 4 + j] = (float)t[j];
  }
  float sum = 0.f;
#pragma unroll
  for (int i = 0; i < 12; ++i) sum += x[i];
  float mean = wave_sum(sum) * (1.0f / CC);
  float s2 = 0.f;
#pragma unroll
  for (int i = 0; i < 12; ++i) { float d = x[i] - mean; s2 += d * d; }
  float rs = rsqrtf(wave_sum(s2) * (1.0f / CC) + EPSF);
#pragma unroll
  for (int s = 0; s < 3; ++s) {
    int cc = s * 256 + c0;
    f32x4 gg = *(const f32x4*)(g + cc);
    f32x4 bb = *(const f32x4*)(b + cc);
    bf16x4 s4 = *(const bf16x4*)(sr + (size_t)row * CC + cc);
    bf16x4 o;
#pragma unroll
    for (int j = 0; j < 4; ++j)
      o[j] = (bf16_t)(((x[s * 4 + j] - mean) * rs * gg[j] + bb[j]) * (float)s4[j]);
    *(bf16x4*)(out + (size_t)row * CC + cc) = o;
  }
}

// ---------------- LN over HID=3072 bf16 rows -> bf16 ----------------
__global__ __launch_bounds__(256) void k_ln_hid(const bf16_t* __restrict__ in,
                                                const float* __restrict__ g,
                                                const float* __restrict__ b,
                                                bf16_t* __restrict__ out, int M) {
  int row = blockIdx.x * 4 + (threadIdx.x >> 6);
  if (row >= M) return;
  int lane = threadIdx.x & 63;
  const bf16_t* rp = in + (size_t)row * HD;
  int c0 = lane * 8;
  bf16x8 x[6];
#pragma unroll
  for (int s = 0; s < 6; ++s) x[s] = *(const bf16x8*)(rp + s * 512 + c0);
  float sum = 0.f;
#pragma unroll
  for (int s = 0; s < 6; ++s)
#pragma unroll
    for (int j = 0; j < 8; ++j) sum += (float)x[s][j];
  float mean = wave_sum(sum) * (1.0f / HD);
  float s2 = 0.f;
#pragma unroll
  for (int s = 0; s < 6; ++s)
#pragma unroll
    for (int j = 0; j < 8; ++j) { float d = (float)x[s][j] - mean; s2 += d * d; }
  float rs = rsqrtf(wave_sum(s2) * (1.0f / HD) + EPSF);
#pragma unroll
  for (int s = 0; s < 6; ++s) {
    int cc = s * 512 + c0;
    f32x4 g0 = *(const f32x4*)(g + cc);
    f32x4 g1 = *(const f32x4*)(g + cc + 4);
    f32x4 b0 = *(const f32x4*)(b + cc);
    f32x4 b1 = *(const f32x4*)(b + cc + 4);
    bf16x8 o;
#pragma unroll
    for (int j = 0; j < 4; ++j) {
      o[j]     = (bf16_t)(((float)x[s][j]     - mean) * rs * g0[j] + b0[j]);
      o[j + 4] = (bf16_t)(((float)x[s][j + 4] - mean) * rs * g1[j] + b1[j]);
    }
    *(bf16x8*)(out + (size_t)row * HD + cc) = o;
  }
}

// ---------------- host orchestration ----------------
struct Layout {
  size_t wk, wv, wr, wo, fk, fv, fr;
  size_t st, big, a16, b16, c16;
  size_t end;
};

static Layout make_layout(int CB) {
  Layout L;
  size_t off = 0;
  auto al = [&](size_t bytes) { size_t o = (off + 255) & ~(size_t)255; off = o + bytes; return o; };
  L.wk = al(589824ull * 2);
  L.wv = al(589824ull * 2);
  L.wr = al(589824ull * 2);
  L.wo = al(589824ull * 2);
  L.fk = al(2359296ull * 2);
  L.fv = al(2359296ull * 2);
  L.fr = al(589824ull * 2);
  size_t M = (size_t)CB * 196;
  size_t MC = M * 768;
  L.st  = al(M * 8);
  L.big = al(MC * 16);   // union: [K32|V32|P16|Q16|R16|SR16] vs [KFa|KFb]
  L.a16 = al(MC * 2);
  L.b16 = al(MC * 2);
  L.c16 = al(MC * 2);
  L.end = off;
  return L;
}

extern "C" void kernel_launch(void* const* d_in, const int* in_sizes, int n_in,
                              void* d_out, int out_size, void* d_ws, size_t ws_size,
                              hipStream_t stream) {
  const float* x      = (const float*)d_in[0];
  const float* ln0_g  = (const float*)d_in[1];
  const float* ln0_b  = (const float*)d_in[2];
  const float* ln1_g  = (const float*)d_in[3];
  const float* ln1_b  = (const float*)d_in[4];
  const float* ln2_g  = (const float*)d_in[5];
  const float* ln2_b  = (const float*)d_in[6];
  const float* amk    = (const float*)d_in[7];
  const float* amv    = (const float*)d_in[8];
  const float* amr    = (const float*)d_in[9];
  const float* adec   = (const float*)d_in[10];
  const float* afirst = (const float*)d_in[11];
  const float* aWk    = (const float*)d_in[12];
  const float* aWv    = (const float*)d_in[13];
  const float* aWr    = (const float*)d_in[14];
  const float* aWo    = (const float*)d_in[15];
  const float* akn_g  = (const float*)d_in[16];
  const float* akn_b  = (const float*)d_in[17];
  const float* fmk    = (const float*)d_in[18];
  const float* fmr    = (const float*)d_in[19];
  const float* fWk    = (const float*)d_in[20];
  const float* fWv    = (const float*)d_in[21];
  const float* fWr    = (const float*)d_in[22];
  const float* fkn_g  = (const float*)d_in[23];
  const float* fkn_b  = (const float*)d_in[24];

  int CB = 32;
  {
    const int cands[3] = {128, 64, 32};
    for (int i = 0; i < 3; ++i)
      if (make_layout(cands[i]).end <= ws_size) { CB = cands[i]; break; }
  }
  Layout L = make_layout(CB);
  int nchunk = 128 / CB;
  int M = CB * 196;
  size_t MC = (size_t)M * 768;

  uint8_t* ws = (uint8_t*)d_ws;
  bf16_t* WkT = (bf16_t*)(ws + L.wk);
  bf16_t* WvT = (bf16_t*)(ws + L.wv);
  bf16_t* WrT = (bf16_t*)(ws + L.wr);
  bf16_t* WoT = (bf16_t*)(ws + L.wo);
  bf16_t* FkT = (bf16_t*)(ws + L.fk);
  bf16_t* FvT = (bf16_t*)(ws + L.fv);
  bf16_t* FrT = (bf16_t*)(ws + L.fr);
  float*  ST  = (float*)(ws + L.st);
  uint8_t* big = ws + L.big;
  float*  K32 = (float*)(big);
  float*  V32 = (float*)(big + MC * 4);
  bf16_t* P16 = (bf16_t*)(big + MC * 8);
  bf16_t* Q16 = (bf16_t*)(big + MC * 10);
  bf16_t* R16 = (bf16_t*)(big + MC * 12);
  bf16_t* SR16 = (bf16_t*)(big + MC * 14);
  bf16_t* KFa = (bf16_t*)(big);            // M x 3072 bf16 (aliases K32..Q16, dead by then)
  bf16_t* KFb = (bf16_t*)(big + MC * 8);   // M x 3072 bf16
  bf16_t* A16 = (bf16_t*)(ws + L.a16);
  bf16_t* B16 = (bf16_t*)(ws + L.b16);
  bf16_t* C16 = (bf16_t*)(ws + L.c16);

  k_tcvt<<<dim3(24, 24), 256, 0, stream>>>(aWk, WkT, 768, 768);
  k_tcvt<<<dim3(24, 24), 256, 0, stream>>>(aWv, WvT, 768, 768);
  k_tcvt<<<dim3(24, 24), 256, 0, stream>>>(aWr, WrT, 768, 768);
  k_tcvt<<<dim3(24, 24), 256, 0, stream>>>(aWo, WoT, 768, 768);
  k_tcvt<<<dim3(96, 24), 256, 0, stream>>>(fWk, FkT, 768, 3072);
  k_tcvt<<<dim3(24, 96), 256, 0, stream>>>(fWv, FvT, 3072, 768);
  k_tcvt<<<dim3(24, 24), 256, 0, stream>>>(fWr, FrT, 768, 768);

  int rowb = M / 4;
  int Mt = M / 128;
  int wkvb = (CB * 768) / 256;

  for (int ch = 0; ch < nchunk; ++ch) {
    const float* xin = x + (size_t)ch * MC;
    float* XB = (float*)d_out + (size_t)ch * MC;   // residual stream lives in d_out

    // ---- attention half ----
    k_ln0<<<rowb, 256, 0, stream>>>(xin, ln0_g, ln0_b, XB, ST, M);
    k_mix<3><<<rowb, 256, 0, stream>>>(XB, ST, ln1_g, ln1_b, amk, amv, amr, A16, B16, C16, M);
    {
      GemmBatch gb{};
      gb.a[0] = {A16, WkT, K32, nullptr, nullptr, EPI_F32, 6};
      gb.a[1] = {B16, WvT, V32, nullptr, nullptr, EPI_F32, 6};
      gb.a[2] = {C16, WrT, SR16, nullptr, nullptr, EPI_SIG_BF16, 6};
      k_gemm<<<dim3(Mt * 18), 256, 0, stream>>>(gb, M, 768, Mt);
    }
    k_wkv_bwd<<<wkvb, 256, 0, stream>>>(K32, V32, adec, P16, Q16, CB);
    k_wkv_fwd<<<wkvb, 256, 0, stream>>>(K32, V32, adec, afirst, P16, Q16, R16, CB);
    k_ln_mul<<<rowb, 256, 0, stream>>>(R16, SR16, akn_g, akn_b, A16, M);
    {
      GemmBatch gb{};
      gb.a[0] = {A16, WoT, XB, nullptr, nullptr, EPI_ADD, 6};
      k_gemm<<<dim3(Mt * 6), 256, 0, stream>>>(gb, M, 768, Mt);
    }

    // ---- ffn half ----
    k_stats<<<rowb, 256, 0, stream>>>(XB, ST, M);
    k_mix<2><<<rowb, 256, 0, stream>>>(XB, ST, ln2_g, ln2_b, fmk, nullptr, fmr, A16, nullptr, C16, M);
    {
      // FFN-K (NT=24) and Wr (NT=6) are independent: fuse into one launch
      GemmBatch gb{};
      gb.a[0] = {A16, FkT, KFa, nullptr, nullptr, EPI_RELU2_BF16, 24};
      gb.a[1] = {C16, FrT, B16, nullptr, nullptr, EPI_SIG_BF16, 6};
      k_gemm<<<dim3(Mt * 30), 256, 0, stream>>>(gb, M, 768, Mt);
    }
    k_ln_hid<<<rowb, 256, 0, stream>>>(KFa, fkn_g, fkn_b, KFb, M);
    {
      GemmBatch gb{};
      gb.a[0] = {KFb, FvT, XB, B16, XB, EPI_GATE, 6};
      k_gemm<<<dim3(Mt * 6), 256, 0, stream>>>(gb, M, 3072, Mt);
    }
  }
}

// Round 6
// 1615.138 us; speedup vs baseline: 3.3997x; 3.3997x over previous
//
#include <hip/hip_runtime.h>
#include <stdint.h>

typedef __bf16 bf16_t;
typedef __bf16 bf16x8 __attribute__((ext_vector_type(8)));
typedef __bf16 bf16x4 __attribute__((ext_vector_type(4)));
typedef float f32x4 __attribute__((ext_vector_type(4)));
typedef unsigned short ushort_t;

#define CC 768
#define HD 3072
#define TB 196
#define HWD 14
#define EPSF 1e-5f
#define INV_T (1.0f/196.0f)

// ---------------- helpers ----------------
__device__ __forceinline__ float wave_sum(float v) {
#pragma unroll
  for (int off = 32; off > 0; off >>= 1) v += __shfl_xor(v, off, 64);
  return v;
}

__device__ __forceinline__ void async_copy16(const void* g, void* l) {
  typedef __attribute__((address_space(3))) uint32_t lds_u32;
  typedef __attribute__((address_space(1))) const uint32_t glb_u32;
  glb_u32* gp = (glb_u32*)(uintptr_t)g;
  lds_u32* lp = (lds_u32*)(uint32_t)(uintptr_t)l;
  __builtin_amdgcn_global_load_lds(gp, lp, 16, 0, 0);
}

#define SCHED_FENCE() asm volatile("" ::: "memory")
#define BAR() asm volatile("s_barrier" ::: "memory")
#define LGKM0() asm volatile("s_waitcnt lgkmcnt(0)" ::: "memory")

// ---------------- LN0 (normalized row to XB + stats of output row) ----------------
__global__ __launch_bounds__(256) void k_ln0(const float* __restrict__ in,
                                             const float* __restrict__ g,
                                             const float* __restrict__ b,
                                             float* __restrict__ out,
                                             float* __restrict__ st, int M) {
  int row = blockIdx.x * 4 + (threadIdx.x >> 6);
  if (row >= M) return;
  int lane = threadIdx.x & 63;
  const float* rp = in + (size_t)row * CC;
  int c0 = lane * 4;
  f32x4 x[3];
#pragma unroll
  for (int s = 0; s < 3; ++s) x[s] = *(const f32x4*)(rp + s * 256 + c0);
  float sum = 0.f;
#pragma unroll
  for (int s = 0; s < 3; ++s)
#pragma unroll
    for (int j = 0; j < 4; ++j) sum += x[s][j];
  float mean = wave_sum(sum) * (1.0f / CC);
  float s2 = 0.f;
#pragma unroll
  for (int s = 0; s < 3; ++s)
#pragma unroll
    for (int j = 0; j < 4; ++j) { float d = x[s][j] - mean; s2 += d * d; }
  float rs = rsqrtf(wave_sum(s2) * (1.0f / CC) + EPSF);
  float* op = out + (size_t)row * CC;
  f32x4 o[3];
  float sum2 = 0.f;
#pragma unroll
  for (int s = 0; s < 3; ++s) {
    int cc = s * 256 + c0;
    f32x4 gg = *(const f32x4*)(g + cc);
    f32x4 bb = *(const f32x4*)(b + cc);
#pragma unroll
    for (int j = 0; j < 4; ++j) {
      o[s][j] = (x[s][j] - mean) * rs * gg[j] + bb[j];
      sum2 += o[s][j];
    }
    *(f32x4*)(op + cc) = o[s];
  }
  float mean2 = wave_sum(sum2) * (1.0f / CC);
  float q2 = 0.f;
#pragma unroll
  for (int s = 0; s < 3; ++s)
#pragma unroll
    for (int j = 0; j < 4; ++j) { float d = o[s][j] - mean2; q2 += d * d; }
  float rs2 = rsqrtf(wave_sum(q2) * (1.0f / CC) + EPSF);
  if (lane == 0) { st[2 * row] = mean2; st[2 * row + 1] = rs2; }
}

// ---------------- per-row mean/rstd ----------------
__global__ __launch_bounds__(256) void k_stats(const float* __restrict__ in,
                                               float* __restrict__ st, int M) {
  int row = blockIdx.x * 4 + (threadIdx.x >> 6);
  if (row >= M) return;
  int lane = threadIdx.x & 63;
  const float* rp = in + (size_t)row * CC;
  int c0 = lane * 4;
  f32x4 x[3];
#pragma unroll
  for (int s = 0; s < 3; ++s) x[s] = *(const f32x4*)(rp + s * 256 + c0);
  float sum = 0.f;
#pragma unroll
  for (int s = 0; s < 3; ++s)
#pragma unroll
    for (int j = 0; j < 4; ++j) sum += x[s][j];
  float mean = wave_sum(sum) * (1.0f / CC);
  float s2 = 0.f;
#pragma unroll
  for (int s = 0; s < 3; ++s)
#pragma unroll
    for (int j = 0; j < 4; ++j) { float d = x[s][j] - mean; s2 += d * d; }
  float rs = rsqrtf(wave_sum(s2) * (1.0f / CC) + EPSF);
  if (lane == 0) { st[2 * row] = mean; st[2 * row + 1] = rs; }
}

// ---------------- LN + q_shift + token-mix, bf16 outputs ----------------
template <int NOUT>
__global__ __launch_bounds__(256) void k_mix(const float* __restrict__ xb,
                                             const float* __restrict__ st,
                                             const float* __restrict__ g,
                                             const float* __restrict__ b,
                                             const float* __restrict__ mk,
                                             const float* __restrict__ mv,
                                             const float* __restrict__ mr,
                                             bf16_t* __restrict__ ok,
                                             bf16_t* __restrict__ ov,
                                             bf16_t* __restrict__ orr, int M) {
  int tok = blockIdx.x * 4 + (threadIdx.x >> 6);
  if (tok >= M) return;
  int lane = threadIdx.x & 63;
  int t = tok % TB;
  int h = t / HWD, w = t % HWD;
  int nbr[4];
  nbr[0] = (w > 0)       ? tok - 1   : -1;
  nbr[1] = (w < HWD - 1) ? tok + 1   : -1;
  nbr[2] = (h > 0)       ? tok - HWD : -1;
  nbr[3] = (h < HWD - 1) ? tok + HWD : -1;
  float ms = st[2 * tok], rss = st[2 * tok + 1];
  const float* rp = xb + (size_t)tok * CC;
#pragma unroll
  for (int s = 0; s < 3; ++s) {
    int cc = s * 256 + lane * 4;
    int grp = cc / 192;
    int nb = nbr[grp];
    f32x4 xs = *(const f32x4*)(rp + cc);
    f32x4 xn = {0.f, 0.f, 0.f, 0.f};
    float mn = 0.f, rsn = 0.f;
    if (nb >= 0) {
      xn = *(const f32x4*)(xb + (size_t)nb * CC + cc);
      mn = st[2 * nb];
      rsn = st[2 * nb + 1];
    }
    f32x4 gg = *(const f32x4*)(g + cc);
    f32x4 bb = *(const f32x4*)(b + cc);
    f32x4 mk4 = *(const f32x4*)(mk + cc);
    f32x4 mr4 = *(const f32x4*)(mr + cc);
    f32x4 mv4 = {0.f, 0.f, 0.f, 0.f};
    if (NOUT == 3) mv4 = *(const f32x4*)(mv + cc);
    bf16x4 vk, vv, vr;
#pragma unroll
    for (int j = 0; j < 4; ++j) {
      float xi = (xs[j] - ms) * rss * gg[j] + bb[j];
      float xx = (nb >= 0) ? ((xn[j] - mn) * rsn * gg[j] + bb[j]) : 0.f;
      vk[j] = (bf16_t)(xi * mk4[j] + xx * (1.0f - mk4[j]));
      if (NOUT == 3) vv[j] = (bf16_t)(xi * mv4[j] + xx * (1.0f - mv4[j]));
      vr[j] = (bf16_t)(xi * mr4[j] + xx * (1.0f - mr4[j]));
    }
    *(bf16x4*)(ok + (size_t)tok * CC + cc) = vk;
    if (NOUT == 3) *(bf16x4*)(ov + (size_t)tok * CC + cc) = vv;
    *(bf16x4*)(orr + (size_t)tok * CC + cc) = vr;
  }
}

// ---------------- weight f32 (K,N) -> bf16 transposed (N,K) ----------------
__global__ __launch_bounds__(256) void k_tcvt(const float* __restrict__ src,
                                              bf16_t* __restrict__ dst, int K, int N) {
  __shared__ float tile[32][33];
  int tx = threadIdx.x & 31;
  int ty = threadIdx.x >> 5;
  int n0 = blockIdx.x * 32, k0 = blockIdx.y * 32;
#pragma unroll
  for (int i = 0; i < 4; ++i)
    tile[ty + 8 * i][tx] = src[(size_t)(k0 + ty + 8 * i) * N + n0 + tx];
  __syncthreads();
#pragma unroll
  for (int i = 0; i < 4; ++i)
    dst[(size_t)(n0 + ty + 8 * i) * K + k0 + tx] = (bf16_t)tile[tx][ty + 8 * i];
}

// ---------------- MFMA GEMM: 128x128, BK=64, A-in-LDS(dbuf) + B-direct, 1 barrier/tile ----------------
// Round-2/4 decomposition: per-CU tile rate stuck ~1750-1830 cy regardless of
// blocks/CU, with LDS (~50%) and L2 (~30%) both unsaturated -> the per-tile
// serial chain isn't overlapping across blocks. Fixes here:
//  (1) setprio REMOVED: with independent co-resident blocks, prio-boosting one
//      block's MFMA starves the others' load issue (m190: setprio hurts 2-phase GEMM).
//  (2) B reads LDS->global direct: B panel/tile = 16 KiB, L1-resident; wn-wave
//      duplication absorbed by L1. Halves LDS traffic (96->48 KiB/blk-tile) and
//      kills the mid-tile barrier + B's in-LDS roundtrip.
//  (3) Load order B(8) then stageA(4) so counted vmcnt(4) drains exactly B
//      before MFMA while A(t+1) stays in flight (drain-0 only on last tile).
//  (4) LDS = A double buffer only (32 KiB). __launch_bounds__(256,3): cap 170
//      VGPR >= ~140 est -> NO spill possible (rounds 3/5 lesson: occupancy
//      steps are 64/128/256; never request a level the registers can't meet).
//      If allocator lands <=128, HW gives 4 blocks/CU for free.
// Per K-tile: {B loads | stageA(t+1)->buf^1 | af ds_reads(buf) | lgkm0 |
// vmcnt(4) | MFMA | vmcnt(0) | BAR}. Single barrier; A-dbuf makes the early
// stage race-free.
enum { EPI_F32 = 0, EPI_SIG_BF16 = 1, EPI_RELU2_BF16 = 2, EPI_ADD = 3, EPI_GATE = 4 };

struct GemmArgs {
  const bf16_t* A;
  const bf16_t* B;
  void* C;
  const bf16_t* gate;   // EPI_GATE
  const float* resid;   // EPI_GATE
  int epi;
  int NT;               // N = NT*128; per-arg so independent gemms fuse in one launch
};
struct GemmBatch { GemmArgs a[3]; };

__global__ __launch_bounds__(256, 3) void k_gemm(GemmBatch batch, int M, int K, int Mt) {
  __shared__ __align__(16) ushort_t sA[2][128 * 64];
  int p = blockIdx.x, zi = 0;
  int nbk = Mt * batch.a[0].NT;
  while (p >= nbk && zi < 2) { p -= nbk; ++zi; nbk = Mt * batch.a[zi].NT; }
  GemmArgs ga = batch.a[zi];
  int NT = ga.NT;
  int N = NT << 7;
  int G = NT * 8, Mt8 = Mt & ~7;
  int m, n;
  if (p < Mt8 * NT) {
    int g = p / G;
    int r = p - g * G;
    m = g * 8 + (r & 7);
    n = r >> 3;
  } else {
    int r2 = p - Mt8 * NT;
    int rem = Mt - Mt8;
    m = Mt8 + r2 % rem;
    n = r2 / rem;
  }
  int bm = m << 7, bn = n << 7;
  int tid = threadIdx.x;
  int wave = tid >> 6, lane = tid & 63;
  int fr = lane & 15, fq = lane >> 4, fr7 = fr & 7;
  int wm = (wave >> 1) * 64, wn = (wave & 1) * 64;
  int r0 = tid >> 3;          // 0..31: base row for A staging
  int pos = tid & 7;          // 16B chunk slot within the 128B LDS row
  int cs = pos ^ (r0 & 7);    // pre-swizzled source chunk ((r0+32j)&7 == r0&7)
  const bf16_t* Ab = ga.A + (size_t)bm * K;
  // this lane's 4 B rows (one per ni), k-chunk fq within each 32-wide k-slice
  const bf16_t* Bw = ga.B + (size_t)(bn + wn + fr) * K + fq * 8;

  auto stageA = [&](int s, int kt) {
    int koff = kt * 64 + cs * 8;
#pragma unroll
    for (int j = 0; j < 4; ++j) {
      int row = j * 32 + r0;
      async_copy16(Ab + (size_t)row * K + koff, &sA[s][row * 64 + pos * 8]);
    }
  };

  f32x4 acc[4][4] = {};
  int niter = K >> 6;
  stageA(0, 0);
  SCHED_FENCE();
  asm volatile("s_waitcnt vmcnt(0)" ::: "memory");
  BAR();
  int buf = 0;
  for (int t = 0; t < niter; ++t) {
    // ---- B fragments direct global->VGPR (8 loads; L1-hot panel) ----
    bf16x8 bfv[4][2];
#pragma unroll
    for (int i = 0; i < 4; ++i)
#pragma unroll
      for (int ks = 0; ks < 2; ++ks)
        bfv[i][ks] = *(const bf16x8*)(Bw + (size_t)(i * 16) * K + t * 64 + ks * 32);
    SCHED_FENCE();
    // ---- A(t+1) staging into the other buffer (4 loads, stays in flight) ----
    if (t + 1 < niter) stageA(buf ^ 1, t + 1);
    SCHED_FENCE();
    // ---- A fragments from LDS ----
    bf16x8 af[4][2];
#pragma unroll
    for (int i = 0; i < 4; ++i) {
      int ra = wm + i * 16 + fr;
#pragma unroll
      for (int ks = 0; ks < 2; ++ks)
        af[i][ks] = *(const bf16x8*)&sA[buf][ra * 64 + (((ks * 4 + fq) ^ fr7) << 3)];
    }
    LGKM0();
    if (t + 1 < niter) asm volatile("s_waitcnt vmcnt(4)" ::: "memory");  // B done, stage in flight
    else               asm volatile("s_waitcnt vmcnt(0)" ::: "memory");
#pragma unroll
    for (int ks = 0; ks < 2; ++ks)
#pragma unroll
      for (int mi = 0; mi < 4; ++mi)
#pragma unroll
        for (int ni = 0; ni < 4; ++ni)
          acc[mi][ni] = __builtin_amdgcn_mfma_f32_16x16x32_bf16(af[mi][ks], bfv[ni][ks], acc[mi][ni], 0, 0, 0);
    asm volatile("s_waitcnt vmcnt(0)" ::: "memory");  // A(t+1) landed for this wave
    BAR();                                            // ... and for all waves
    buf ^= 1;
  }
  int epi = ga.epi;
#pragma unroll
  for (int mi = 0; mi < 4; ++mi) {
#pragma unroll
    for (int ni = 0; ni < 4; ++ni) {
#pragma unroll
      for (int r = 0; r < 4; ++r) {
        int grow = bm + wm + mi * 16 + fq * 4 + r;
        int gcol = bn + wn + ni * 16 + fr;
        size_t idx = (size_t)grow * N + gcol;
        float v = acc[mi][ni][r];
        if (epi == EPI_F32) {
          ((float*)ga.C)[idx] = v;
        } else if (epi == EPI_SIG_BF16) {
          ((bf16_t*)ga.C)[idx] = (bf16_t)(1.0f / (1.0f + __expf(-v)));
        } else if (epi == EPI_RELU2_BF16) {
          float tv = v > 0.f ? v : 0.f;
          ((bf16_t*)ga.C)[idx] = (bf16_t)(tv * tv);
        } else if (epi == EPI_ADD) {
          ((float*)ga.C)[idx] += v;
        } else {  // EPI_GATE: out = resid + sigmoid-gate * v
          ((float*)ga.C)[idx] = ga.resid[idx] + (float)ga.gate[idx] * v;
        }
      }
    }
  }
}

// ---------------- bidirectional WKV scans ----------------
__global__ __launch_bounds__(256) void k_wkv_bwd(const float* __restrict__ k,
                                                 const float* __restrict__ v,
                                                 const float* __restrict__ decay,
                                                 bf16_t* __restrict__ ba,
                                                 bf16_t* __restrict__ bb, int CB) {
  int idx = blockIdx.x * 256 + threadIdx.x;
  if (idx >= CB * CC) return;
  int c = idx % CC;
  size_t base = (size_t)(idx / CC) * TB * CC + c;
  float w = decay[c] * INV_T;
  float d = __expf(-w);
  float a = 0.f, bs = 0.f;
  for (int t = TB - 1; t >= 0; --t) {
    size_t p = base + (size_t)t * CC;
    ba[p] = (bf16_t)a;
    bb[p] = (bf16_t)bs;
    float ek = __expf(k[p]);
    a = d * (a + ek * v[p]);
    bs = d * (bs + ek);
  }
}

__global__ __launch_bounds__(256) void k_wkv_fwd(const float* __restrict__ k,
                                                 const float* __restrict__ v,
                                                 const float* __restrict__ decay,
                                                 const float* __restrict__ first,
                                                 const bf16_t* __restrict__ ba,
                                                 const bf16_t* __restrict__ bb,
                                                 bf16_t* __restrict__ r, int CB) {
  int idx = blockIdx.x * 256 + threadIdx.x;
  if (idx >= CB * CC) return;
  int c = idx % CC;
  size_t base = (size_t)(idx / CC) * TB * CC + c;
  float w = decay[c] * INV_T;
  float d = __expf(-w);
  float ew = __expf(w);
  float u = first[c] * INV_T;
  float a = 0.f, bs = 0.f;
  for (int t = 0; t < TB; ++t) {
    size_t p = base + (size_t)t * CC;
    float kk = k[p], vv = v[p];
    float eu = __expf(u + kk);
    float num = ew * (a + (float)ba[p]) + eu * vv;
    float den = ew * (bs + (float)bb[p]) + eu;
    r[p] = (bf16_t)(num / den);
    float ek = __expf(kk);
    a = d * (a + ek * vv);
    bs = d * (bs + ek);
  }
}

// ---------------- LN(rwkv bf16) * sr -> bf16 ----------------
__global__ __launch_bounds__(256) void k_ln_mul(const bf16_t* __restrict__ in,
                                                const bf16_t* __restrict__ sr,
                                                const float* __restrict__ g,
                                                const float* __restrict__ b,
                                                bf16_t* __restrict__ out, int M) {
  int row = blockIdx.x * 4 + (threadIdx.x >> 6);
  if (row >= M) return;
  int lane = threadIdx.x & 63;
  const bf16_t* rp = in + (size_t)row * CC;
  int c0 = lane * 4;
  float x[12];
#pragma unroll
  for (int s = 0; s < 3; ++s) {
    bf16x4 t = *(const bf16x4*)(rp + s * 256 + c0);
#pragma unroll
    for (int j = 0; j < 4; ++j) x[s * 4 + j] = (float)t[j];
  }
  float sum = 0.f;
#pragma unroll
  for (int i = 0; i < 12; ++i) sum += x[i];
  float mean = wave_sum(sum) * (1.0f / CC);
  float s2 = 0.f;
#pragma unroll
  for (int i = 0; i < 12; ++i) { float d = x[i] - mean; s2 += d * d; }
  float rs = rsqrtf(wave_sum(s2) * (1.0f / CC) + EPSF);
#pragma unroll
  for (int s = 0; s < 3; ++s) {
    int cc = s * 256 + c0;
    f32x4 gg = *(const f32x4*)(g + cc);
    f32x4 bb = *(const f32x4*)(b + cc);
    bf16x4 s4 = *(const bf16x4*)(sr + (size_t)row * CC + cc);
    bf16x4 o;
#pragma unroll
    for (int j = 0; j < 4; ++j)
      o[j] = (bf16_t)(((x[s * 4 + j] - mean) * rs * gg[j] + bb[j]) * (float)s4[j]);
    *(bf16x4*)(out + (size_t)row * CC + cc) = o;
  }
}

// ---------------- LN over HID=3072 bf16 rows -> bf16 ----------------
__global__ __launch_bounds__(256) void k_ln_hid(const bf16_t* __restrict__ in,
                                                const float* __restrict__ g,
                                                const float* __restrict__ b,
                                                bf16_t* __restrict__ out, int M) {
  int row = blockIdx.x * 4 + (threadIdx.x >> 6);
  if (row >= M) return;
  int lane = threadIdx.x & 63;
  const bf16_t* rp = in + (size_t)row * HD;
  int c0 = lane * 8;
  bf16x8 x[6];
#pragma unroll
  for (int s = 0; s < 6; ++s) x[s] = *(const bf16x8*)(rp + s * 512 + c0);
  float sum = 0.f;
#pragma unroll
  for (int s = 0; s < 6; ++s)
#pragma unroll
    for (int j = 0; j < 8; ++j) sum += (float)x[s][j];
  float mean = wave_sum(sum) * (1.0f / HD);
  float s2 = 0.f;
#pragma unroll
  for (int s = 0; s < 6; ++s)
#pragma unroll
    for (int j = 0; j < 8; ++j) { float d = (float)x[s][j] - mean; s2 += d * d; }
  float rs = rsqrtf(wave_sum(s2) * (1.0f / HD) + EPSF);
#pragma unroll
  for (int s = 0; s < 6; ++s) {
    int cc = s * 512 + c0;
    f32x4 g0 = *(const f32x4*)(g + cc);
    f32x4 g1 = *(const f32x4*)(g + cc + 4);
    f32x4 b0 = *(const f32x4*)(b + cc);
    f32x4 b1 = *(const f32x4*)(b + cc + 4);
    bf16x8 o;
#pragma unroll
    for (int j = 0; j < 4; ++j) {
      o[j]     = (bf16_t)(((float)x[s][j]     - mean) * rs * g0[j] + b0[j]);
      o[j + 4] = (bf16_t)(((float)x[s][j + 4] - mean) * rs * g1[j] + b1[j]);
    }
    *(bf16x8*)(out + (size_t)row * HD + cc) = o;
  }
}

// ---------------- host orchestration ----------------
struct Layout {
  size_t wk, wv, wr, wo, fk, fv, fr;
  size_t st, big, a16, b16, c16;
  size_t end;
};

static Layout make_layout(int CB) {
  Layout L;
  size_t off = 0;
  auto al = [&](size_t bytes) { size_t o = (off + 255) & ~(size_t)255; off = o + bytes; return o; };
  L.wk = al(589824ull * 2);
  L.wv = al(589824ull * 2);
  L.wr = al(589824ull * 2);
  L.wo = al(589824ull * 2);
  L.fk = al(2359296ull * 2);
  L.fv = al(2359296ull * 2);
  L.fr = al(589824ull * 2);
  size_t M = (size_t)CB * 196;
  size_t MC = M * 768;
  L.st  = al(M * 8);
  L.big = al(MC * 16);   // union: [K32|V32|P16|Q16|R16|SR16] vs [KFa|KFb]
  L.a16 = al(MC * 2);
  L.b16 = al(MC * 2);
  L.c16 = al(MC * 2);
  L.end = off;
  return L;
}

extern "C" void kernel_launch(void* const* d_in, const int* in_sizes, int n_in,
                              void* d_out, int out_size, void* d_ws, size_t ws_size,
                              hipStream_t stream) {
  const float* x      = (const float*)d_in[0];
  const float* ln0_g  = (const float*)d_in[1];
  const float* ln0_b  = (const float*)d_in[2];
  const float* ln1_g  = (const float*)d_in[3];
  const float* ln1_b  = (const float*)d_in[4];
  const float* ln2_g  = (const float*)d_in[5];
  const float* ln2_b  = (const float*)d_in[6];
  const float* amk    = (const float*)d_in[7];
  const float* amv    = (const float*)d_in[8];
  const float* amr    = (const float*)d_in[9];
  const float* adec   = (const float*)d_in[10];
  const float* afirst = (const float*)d_in[11];
  const float* aWk    = (const float*)d_in[12];
  const float* aWv    = (const float*)d_in[13];
  const float* aWr    = (const float*)d_in[14];
  const float* aWo    = (const float*)d_in[15];
  const float* akn_g  = (const float*)d_in[16];
  const float* akn_b  = (const float*)d_in[17];
  const float* fmk    = (const float*)d_in[18];
  const float* fmr    = (const float*)d_in[19];
  const float* fWk    = (const float*)d_in[20];
  const float* fWv    = (const float*)d_in[21];
  const float* fWr    = (const float*)d_in[22];
  const float* fkn_g  = (const float*)d_in[23];
  const float* fkn_b  = (const float*)d_in[24];

  int CB = 32;
  {
    const int cands[3] = {128, 64, 32};
    for (int i = 0; i < 3; ++i)
      if (make_layout(cands[i]).end <= ws_size) { CB = cands[i]; break; }
  }
  Layout L = make_layout(CB);
  int nchunk = 128 / CB;
  int M = CB * 196;
  size_t MC = (size_t)M * 768;

  uint8_t* ws = (uint8_t*)d_ws;
  bf16_t* WkT = (bf16_t*)(ws + L.wk);
  bf16_t* WvT = (bf16_t*)(ws + L.wv);
  bf16_t* WrT = (bf16_t*)(ws + L.wr);
  bf16_t* WoT = (bf16_t*)(ws + L.wo);
  bf16_t* FkT = (bf16_t*)(ws + L.fk);
  bf16_t* FvT = (bf16_t*)(ws + L.fv);
  bf16_t* FrT = (bf16_t*)(ws + L.fr);
  float*  ST  = (float*)(ws + L.st);
  uint8_t* big = ws + L.big;
  float*  K32 = (float*)(big);
  float*  V32 = (float*)(big + MC * 4);
  bf16_t* P16 = (bf16_t*)(big + MC * 8);
  bf16_t* Q16 = (bf16_t*)(big + MC * 10);
  bf16_t* R16 = (bf16_t*)(big + MC * 12);
  bf16_t* SR16 = (bf16_t*)(big + MC * 14);
  bf16_t* KFa = (bf16_t*)(big);            // M x 3072 bf16 (aliases K32..Q16, dead by then)
  bf16_t* KFb = (bf16_t*)(big + MC * 8);   // M x 3072 bf16
  bf16_t* A16 = (bf16_t*)(ws + L.a16);
  bf16_t* B16 = (bf16_t*)(ws + L.b16);
  bf16_t* C16 = (bf16_t*)(ws + L.c16);

  k_tcvt<<<dim3(24, 24), 256, 0, stream>>>(aWk, WkT, 768, 768);
  k_tcvt<<<dim3(24, 24), 256, 0, stream>>>(aWv, WvT, 768, 768);
  k_tcvt<<<dim3(24, 24), 256, 0, stream>>>(aWr, WrT, 768, 768);
  k_tcvt<<<dim3(24, 24), 256, 0, stream>>>(aWo, WoT, 768, 768);
  k_tcvt<<<dim3(96, 24), 256, 0, stream>>>(fWk, FkT, 768, 3072);
  k_tcvt<<<dim3(24, 96), 256, 0, stream>>>(fWv, FvT, 3072, 768);
  k_tcvt<<<dim3(24, 24), 256, 0, stream>>>(fWr, FrT, 768, 768);

  int rowb = M / 4;
  int Mt = M / 128;
  int wkvb = (CB * 768) / 256;

  for (int ch = 0; ch < nchunk; ++ch) {
    const float* xin = x + (size_t)ch * MC;
    float* XB = (float*)d_out + (size_t)ch * MC;   // residual stream lives in d_out

    // ---- attention half ----
    k_ln0<<<rowb, 256, 0, stream>>>(xin, ln0_g, ln0_b, XB, ST, M);
    k_mix<3><<<rowb, 256, 0, stream>>>(XB, ST, ln1_g, ln1_b, amk, amv, amr, A16, B16, C16, M);
    {
      GemmBatch gb{};
      gb.a[0] = {A16, WkT, K32, nullptr, nullptr, EPI_F32, 6};
      gb.a[1] = {B16, WvT, V32, nullptr, nullptr, EPI_F32, 6};
      gb.a[2] = {C16, WrT, SR16, nullptr, nullptr, EPI_SIG_BF16, 6};
      k_gemm<<<dim3(Mt * 18), 256, 0, stream>>>(gb, M, 768, Mt);
    }
    k_wkv_bwd<<<wkvb, 256, 0, stream>>>(K32, V32, adec, P16, Q16, CB);
    k_wkv_fwd<<<wkvb, 256, 0, stream>>>(K32, V32, adec, afirst, P16, Q16, R16, CB);
    k_ln_mul<<<rowb, 256, 0, stream>>>(R16, SR16, akn_g, akn_b, A16, M);
    {
      GemmBatch gb{};
      gb.a[0] = {A16, WoT, XB, nullptr, nullptr, EPI_ADD, 6};
      k_gemm<<<dim3(Mt * 6), 256, 0, stream>>>(gb, M, 768, Mt);
    }

    // ---- ffn half ----
    k_stats<<<rowb, 256, 0, stream>>>(XB, ST, M);
    k_mix<2><<<rowb, 256, 0, stream>>>(XB, ST, ln2_g, ln2_b, fmk, nullptr, fmr, A16, nullptr, C16, M);
    {
      // FFN-K (NT=24) and Wr (NT=6) are independent: fuse into one launch
      GemmBatch gb{};
      gb.a[0] = {A16, FkT, KFa, nullptr, nullptr, EPI_RELU2_BF16, 24};
      gb.a[1] = {C16, FrT, B16, nullptr, nullptr, EPI_SIG_BF16, 6};
      k_gemm<<<dim3(Mt * 30), 256, 0, stream>>>(gb, M, 768, Mt);
    }
    k_ln_hid<<<rowb, 256, 0, stream>>>(KFa, fkn_g, fkn_b, KFb, M);
    {
      GemmBatch gb{};
      gb.a[0] = {KFb, FvT, XB, B16, XB, EPI_GATE, 6};
      k_gemm<<<dim3(Mt * 6), 256, 0, stream>>>(gb, M, 3072, Mt);
    }
  }
}

// Round 7
// 1075.452 us; speedup vs baseline: 5.1058x; 1.5018x over previous
//
#include <hip/hip_runtime.h>
#include <stdint.h>

typedef __bf16 bf16_t;
typedef __bf16 bf16x8 __attribute__((ext_vector_type(8)));
typedef __bf16 bf16x4 __attribute__((ext_vector_type(4)));
typedef float f32x4 __attribute__((ext_vector_type(4)));
typedef unsigned short ushort_t;

#define CC 768
#define HD 3072
#define TB 196
#define HWD 14
#define EPSF 1e-5f
#define INV_T (1.0f/196.0f)

// ---------------- helpers ----------------
__device__ __forceinline__ float wave_sum(float v) {
#pragma unroll
  for (int off = 32; off > 0; off >>= 1) v += __shfl_xor(v, off, 64);
  return v;
}

__device__ __forceinline__ void async_copy16(const void* g, void* l) {
  typedef __attribute__((address_space(3))) uint32_t lds_u32;
  typedef __attribute__((address_space(1))) const uint32_t glb_u32;
  glb_u32* gp = (glb_u32*)(uintptr_t)g;
  lds_u32* lp = (lds_u32*)(uint32_t)(uintptr_t)l;
  __builtin_amdgcn_global_load_lds(gp, lp, 16, 0, 0);
}

#define SCHED_FENCE() asm volatile("" ::: "memory")
#define BAR() asm volatile("s_barrier" ::: "memory")
#define LGKM0() asm volatile("s_waitcnt lgkmcnt(0)" ::: "memory")

// ---------------- LN0 (normalized row to XB + stats of output row) ----------------
__global__ __launch_bounds__(256) void k_ln0(const float* __restrict__ in,
                                             const float* __restrict__ g,
                                             const float* __restrict__ b,
                                             float* __restrict__ out,
                                             float* __restrict__ st, int M) {
  int row = blockIdx.x * 4 + (threadIdx.x >> 6);
  if (row >= M) return;
  int lane = threadIdx.x & 63;
  const float* rp = in + (size_t)row * CC;
  int c0 = lane * 4;
  f32x4 x[3];
#pragma unroll
  for (int s = 0; s < 3; ++s) x[s] = *(const f32x4*)(rp + s * 256 + c0);
  float sum = 0.f;
#pragma unroll
  for (int s = 0; s < 3; ++s)
#pragma unroll
    for (int j = 0; j < 4; ++j) sum += x[s][j];
  float mean = wave_sum(sum) * (1.0f / CC);
  float s2 = 0.f;
#pragma unroll
  for (int s = 0; s < 3; ++s)
#pragma unroll
    for (int j = 0; j < 4; ++j) { float d = x[s][j] - mean; s2 += d * d; }
  float rs = rsqrtf(wave_sum(s2) * (1.0f / CC) + EPSF);
  float* op = out + (size_t)row * CC;
  f32x4 o[3];
  float sum2 = 0.f;
#pragma unroll
  for (int s = 0; s < 3; ++s) {
    int cc = s * 256 + c0;
    f32x4 gg = *(const f32x4*)(g + cc);
    f32x4 bb = *(const f32x4*)(b + cc);
#pragma unroll
    for (int j = 0; j < 4; ++j) {
      o[s][j] = (x[s][j] - mean) * rs * gg[j] + bb[j];
      sum2 += o[s][j];
    }
    *(f32x4*)(op + cc) = o[s];
  }
  float mean2 = wave_sum(sum2) * (1.0f / CC);
  float q2 = 0.f;
#pragma unroll
  for (int s = 0; s < 3; ++s)
#pragma unroll
    for (int j = 0; j < 4; ++j) { float d = o[s][j] - mean2; q2 += d * d; }
  float rs2 = rsqrtf(wave_sum(q2) * (1.0f / CC) + EPSF);
  if (lane == 0) { st[2 * row] = mean2; st[2 * row + 1] = rs2; }
}

// ---------------- per-row mean/rstd ----------------
__global__ __launch_bounds__(256) void k_stats(const float* __restrict__ in,
                                               float* __restrict__ st, int M) {
  int row = blockIdx.x * 4 + (threadIdx.x >> 6);
  if (row >= M) return;
  int lane = threadIdx.x & 63;
  const float* rp = in + (size_t)row * CC;
  int c0 = lane * 4;
  f32x4 x[3];
#pragma unroll
  for (int s = 0; s < 3; ++s) x[s] = *(const f32x4*)(rp + s * 256 + c0);
  float sum = 0.f;
#pragma unroll
  for (int s = 0; s < 3; ++s)
#pragma unroll
    for (int j = 0; j < 4; ++j) sum += x[s][j];
  float mean = wave_sum(sum) * (1.0f / CC);
  float s2 = 0.f;
#pragma unroll
  for (int s = 0; s < 3; ++s)
#pragma unroll
    for (int j = 0; j < 4; ++j) { float d = x[s][j] - mean; s2 += d * d; }
  float rs = rsqrtf(wave_sum(s2) * (1.0f / CC) + EPSF);
  if (lane == 0) { st[2 * row] = mean; st[2 * row + 1] = rs; }
}

// ---------------- LN + q_shift + token-mix, bf16 outputs ----------------
template <int NOUT>
__global__ __launch_bounds__(256) void k_mix(const float* __restrict__ xb,
                                             const float* __restrict__ st,
                                             const float* __restrict__ g,
                                             const float* __restrict__ b,
                                             const float* __restrict__ mk,
                                             const float* __restrict__ mv,
                                             const float* __restrict__ mr,
                                             bf16_t* __restrict__ ok,
                                             bf16_t* __restrict__ ov,
                                             bf16_t* __restrict__ orr, int M) {
  int tok = blockIdx.x * 4 + (threadIdx.x >> 6);
  if (tok >= M) return;
  int lane = threadIdx.x & 63;
  int t = tok % TB;
  int h = t / HWD, w = t % HWD;
  int nbr[4];
  nbr[0] = (w > 0)       ? tok - 1   : -1;
  nbr[1] = (w < HWD - 1) ? tok + 1   : -1;
  nbr[2] = (h > 0)       ? tok - HWD : -1;
  nbr[3] = (h < HWD - 1) ? tok + HWD : -1;
  float ms = st[2 * tok], rss = st[2 * tok + 1];
  const float* rp = xb + (size_t)tok * CC;
#pragma unroll
  for (int s = 0; s < 3; ++s) {
    int cc = s * 256 + lane * 4;
    int grp = cc / 192;
    int nb = nbr[grp];
    f32x4 xs = *(const f32x4*)(rp + cc);
    f32x4 xn = {0.f, 0.f, 0.f, 0.f};
    float mn = 0.f, rsn = 0.f;
    if (nb >= 0) {
      xn = *(const f32x4*)(xb + (size_t)nb * CC + cc);
      mn = st[2 * nb];
      rsn = st[2 * nb + 1];
    }
    f32x4 gg = *(const f32x4*)(g + cc);
    f32x4 bb = *(const f32x4*)(b + cc);
    f32x4 mk4 = *(const f32x4*)(mk + cc);
    f32x4 mr4 = *(const f32x4*)(mr + cc);
    f32x4 mv4 = {0.f, 0.f, 0.f, 0.f};
    if (NOUT == 3) mv4 = *(const f32x4*)(mv + cc);
    bf16x4 vk, vv, vr;
#pragma unroll
    for (int j = 0; j < 4; ++j) {
      float xi = (xs[j] - ms) * rss * gg[j] + bb[j];
      float xx = (nb >= 0) ? ((xn[j] - mn) * rsn * gg[j] + bb[j]) : 0.f;
      vk[j] = (bf16_t)(xi * mk4[j] + xx * (1.0f - mk4[j]));
      if (NOUT == 3) vv[j] = (bf16_t)(xi * mv4[j] + xx * (1.0f - mv4[j]));
      vr[j] = (bf16_t)(xi * mr4[j] + xx * (1.0f - mr4[j]));
    }
    *(bf16x4*)(ok + (size_t)tok * CC + cc) = vk;
    if (NOUT == 3) *(bf16x4*)(ov + (size_t)tok * CC + cc) = vv;
    *(bf16x4*)(orr + (size_t)tok * CC + cc) = vr;
  }
}

// ---------------- weight f32 (K,N) -> bf16 transposed (N,K) ----------------
__global__ __launch_bounds__(256) void k_tcvt(const float* __restrict__ src,
                                              bf16_t* __restrict__ dst, int K, int N) {
  __shared__ float tile[32][33];
  int tx = threadIdx.x & 31;
  int ty = threadIdx.x >> 5;
  int n0 = blockIdx.x * 32, k0 = blockIdx.y * 32;
#pragma unroll
  for (int i = 0; i < 4; ++i)
    tile[ty + 8 * i][tx] = src[(size_t)(k0 + ty + 8 * i) * N + n0 + tx];
  __syncthreads();
#pragma unroll
  for (int i = 0; i < 4; ++i)
    dst[(size_t)(n0 + ty + 8 * i) * K + k0 + tx] = (bf16_t)tile[tx][ty + 8 * i];
}

// z-batched 768x768 transposes (one launch for the 5 square weights)
struct TcvtPair { const float* src; bf16_t* dst; };
struct TcvtBatch { TcvtPair p[5]; };
__global__ __launch_bounds__(256) void k_tcvt5(TcvtBatch tb) {
  __shared__ float tile[32][33];
  TcvtPair pp = tb.p[blockIdx.z];
  int tx = threadIdx.x & 31;
  int ty = threadIdx.x >> 5;
  int n0 = blockIdx.x * 32, k0 = blockIdx.y * 32;
#pragma unroll
  for (int i = 0; i < 4; ++i)
    tile[ty + 8 * i][tx] = pp.src[(size_t)(k0 + ty + 8 * i) * 768 + n0 + tx];
  __syncthreads();
#pragma unroll
  for (int i = 0; i < 4; ++i)
    pp.dst[(size_t)(n0 + ty + 8 * i) * 768 + k0 + tx] = (bf16_t)tile[tx][ty + 8 * i];
}

// ---------------- MFMA GEMM: 128x128, BK=64, A-dbuf + B-single, 48 KiB, 3 blocks/CU ----------------
// Round-4 structure (session best), setprio REMOVED (m190: setprio is negative
// on multi-block 2-phase GEMM - it starves co-resident blocks' load issue).
// Per K-tile: {stageA(t+1)->buf^1 (early, race-free via dbuf) | read B frags |
// lgkm0 | BAR | stageB(t+1) | read A frags | lgkm0 | MFMA | vmcnt(0) | BAR}.
enum { EPI_F32 = 0, EPI_SIG_BF16 = 1, EPI_RELU2_BF16 = 2, EPI_ADD = 3, EPI_GATE = 4 };

struct GemmArgs {
  const bf16_t* A;
  const bf16_t* B;
  void* C;
  const bf16_t* gate;   // EPI_GATE
  const float* resid;   // EPI_GATE
  int epi;
  int NT;               // N = NT*128; per-arg so independent gemms fuse in one launch
};
struct GemmBatch { GemmArgs a[3]; };

__global__ __launch_bounds__(256, 3) void k_gemm(GemmBatch batch, int M, int K, int Mt) {
  __shared__ __align__(16) ushort_t sA[2][128 * 64];
  __shared__ __align__(16) ushort_t sB[128 * 64];
  int p = blockIdx.x, zi = 0;
  int nbk = Mt * batch.a[0].NT;
  while (p >= nbk && zi < 2) { p -= nbk; ++zi; nbk = Mt * batch.a[zi].NT; }
  GemmArgs ga = batch.a[zi];
  int NT = ga.NT;
  int N = NT << 7;
  int G = NT * 8, Mt8 = Mt & ~7;
  int m, n;
  if (p < Mt8 * NT) {
    int g = p / G;
    int r = p - g * G;
    m = g * 8 + (r & 7);
    n = r >> 3;
  } else {
    int r2 = p - Mt8 * NT;
    int rem = Mt - Mt8;
    m = Mt8 + r2 % rem;
    n = r2 / rem;
  }
  int bm = m << 7, bn = n << 7;
  int tid = threadIdx.x;
  int wave = tid >> 6, lane = tid & 63;
  int fr = lane & 15, fq = lane >> 4, fr7 = fr & 7;
  int wm = (wave >> 1) * 64, wn = (wave & 1) * 64;
  int r0 = tid >> 3;          // 0..31: base row for staging
  int pos = tid & 7;          // 16B chunk slot within the 128B LDS row
  int cs = pos ^ (r0 & 7);    // pre-swizzled source chunk ((r0+32j)&7 == r0&7)
  const bf16_t* Ab = ga.A + (size_t)bm * K;
  const bf16_t* Bb = ga.B + (size_t)bn * K;

  auto stageA = [&](int s, int kt) {
    int koff = kt * 64 + cs * 8;
#pragma unroll
    for (int j = 0; j < 4; ++j) {
      int row = j * 32 + r0;
      async_copy16(Ab + (size_t)row * K + koff, &sA[s][row * 64 + pos * 8]);
    }
  };
  auto stageB = [&](int kt) {
    int koff = kt * 64 + cs * 8;
#pragma unroll
    for (int j = 0; j < 4; ++j) {
      int row = j * 32 + r0;
      async_copy16(Bb + (size_t)row * K + koff, &sB[row * 64 + pos * 8]);
    }
  };

  f32x4 acc[4][4] = {};
  int niter = K >> 6;
  stageA(0, 0);
  stageB(0);
  SCHED_FENCE();
  asm volatile("s_waitcnt vmcnt(0)" ::: "memory");
  BAR();
  int buf = 0;
  for (int t = 0; t < niter; ++t) {
    // A(t) in sA[buf], B(t) in sB, both landed (tail vmcnt+BAR of prev iter).
    if (t + 1 < niter) stageA(buf ^ 1, t + 1);   // double-buffered: race-free early issue
    SCHED_FENCE();
    bf16x8 bfv[4][2];
#pragma unroll
    for (int i = 0; i < 4; ++i) {
      int rb = wn + i * 16 + fr;
#pragma unroll
      for (int ks = 0; ks < 2; ++ks)
        bfv[i][ks] = *(const bf16x8*)&sB[rb * 64 + (((ks * 4 + fq) ^ fr7) << 3)];
    }
    LGKM0();            // own B reads done
    BAR();              // ALL waves' B reads done -> sB safe to overwrite
    if (t + 1 < niter) stageB(t + 1);
    SCHED_FENCE();
    bf16x8 af[4][2];
#pragma unroll
    for (int i = 0; i < 4; ++i) {
      int ra = wm + i * 16 + fr;
#pragma unroll
      for (int ks = 0; ks < 2; ++ks)
        af[i][ks] = *(const bf16x8*)&sA[buf][ra * 64 + (((ks * 4 + fq) ^ fr7) << 3)];
    }
    LGKM0();
#pragma unroll
    for (int ks = 0; ks < 2; ++ks)
#pragma unroll
      for (int mi = 0; mi < 4; ++mi)
#pragma unroll
        for (int ni = 0; ni < 4; ++ni)
          acc[mi][ni] = __builtin_amdgcn_mfma_f32_16x16x32_bf16(af[mi][ks], bfv[ni][ks], acc[mi][ni], 0, 0, 0);
    asm volatile("s_waitcnt vmcnt(0)" ::: "memory");  // A(t+1), B(t+1) landed
    BAR();
    buf ^= 1;
  }
  int epi = ga.epi;
#pragma unroll
  for (int mi = 0; mi < 4; ++mi) {
#pragma unroll
    for (int ni = 0; ni < 4; ++ni) {
#pragma unroll
      for (int r = 0; r < 4; ++r) {
        int grow = bm + wm + mi * 16 + fq * 4 + r;
        int gcol = bn + wn + ni * 16 + fr;
        size_t idx = (size_t)grow * N + gcol;
        float v = acc[mi][ni][r];
        if (epi == EPI_F32) {
          ((float*)ga.C)[idx] = v;
        } else if (epi == EPI_SIG_BF16) {
          ((bf16_t*)ga.C)[idx] = (bf16_t)(1.0f / (1.0f + __expf(-v)));
        } else if (epi == EPI_RELU2_BF16) {
          float tv = v > 0.f ? v : 0.f;
          ((bf16_t*)ga.C)[idx] = (bf16_t)(tv * tv);
        } else if (epi == EPI_ADD) {
          ((float*)ga.C)[idx] += v;
        } else {  // EPI_GATE: out = resid + sigmoid-gate * v
          ((float*)ga.C)[idx] = ga.resid[idx] + (float)ga.gate[idx] * v;
        }
      }
    }
  }
}

// ---------------- bidirectional WKV scans ----------------
__global__ __launch_bounds__(256) void k_wkv_bwd(const float* __restrict__ k,
                                                 const float* __restrict__ v,
                                                 const float* __restrict__ decay,
                                                 bf16_t* __restrict__ ba,
                                                 bf16_t* __restrict__ bb, int CB) {
  int idx = blockIdx.x * 256 + threadIdx.x;
  if (idx >= CB * CC) return;
  int c = idx % CC;
  size_t base = (size_t)(idx / CC) * TB * CC + c;
  float w = decay[c] * INV_T;
  float d = __expf(-w);
  float a = 0.f, bs = 0.f;
  for (int t = TB - 1; t >= 0; --t) {
    size_t p = base + (size_t)t * CC;
    ba[p] = (bf16_t)a;
    bb[p] = (bf16_t)bs;
    float ek = __expf(k[p]);
    a = d * (a + ek * v[p]);
    bs = d * (bs + ek);
  }
}

__global__ __launch_bounds__(256) void k_wkv_fwd(const float* __restrict__ k,
                                                 const float* __restrict__ v,
                                                 const float* __restrict__ decay,
                                                 const float* __restrict__ first,
                                                 const bf16_t* __restrict__ ba,
                                                 const bf16_t* __restrict__ bb,
                                                 bf16_t* __restrict__ r, int CB) {
  int idx = blockIdx.x * 256 + threadIdx.x;
  if (idx >= CB * CC) return;
  int c = idx % CC;
  size_t base = (size_t)(idx / CC) * TB * CC + c;
  float w = decay[c] * INV_T;
  float d = __expf(-w);
  float ew = __expf(w);
  float u = first[c] * INV_T;
  float a = 0.f, bs = 0.f;
  for (int t = 0; t < TB; ++t) {
    size_t p = base + (size_t)t * CC;
    float kk = k[p], vv = v[p];
    float eu = __expf(u + kk);
    float num = ew * (a + (float)ba[p]) + eu * vv;
    float den = ew * (bs + (float)bb[p]) + eu;
    r[p] = (bf16_t)(num / den);
    float ek = __expf(kk);
    a = d * (a + ek * vv);
    bs = d * (bs + ek);
  }
}

// ---------------- LN(rwkv bf16) * sr -> bf16 ----------------
__global__ __launch_bounds__(256) void k_ln_mul(const bf16_t* __restrict__ in,
                                                const bf16_t* __restrict__ sr,
                                                const float* __restrict__ g,
                                                const float* __restrict__ b,
                                                bf16_t* __restrict__ out, int M) {
  int row = blockIdx.x * 4 + (threadIdx.x >> 6);
  if (row >= M) return;
  int lane = threadIdx.x & 63;
  const bf16_t* rp = in + (size_t)row * CC;
  int c0 = lane * 4;
  float x[12];
#pragma unroll
  for (int s = 0; s < 3; ++s) {
    bf16x4 t = *(const bf16x4*)(rp + s * 256 + c0);
#pragma unroll
    for (int j = 0; j < 4; ++j) x[s * 4 + j] = (float)t[j];
  }
  float sum = 0.f;
#pragma unroll
  for (int i = 0; i < 12; ++i) sum += x[i];
  float mean = wave_sum(sum) * (1.0f / CC);
  float s2 = 0.f;
#pragma unroll
  for (int i = 0; i < 12; ++i) { float d = x[i] - mean; s2 += d * d; }
  float rs = rsqrtf(wave_sum(s2) * (1.0f / CC) + EPSF);
#pragma unroll
  for (int s = 0; s < 3; ++s) {
    int cc = s * 256 + c0;
    f32x4 gg = *(const f32x4*)(g + cc);
    f32x4 bb = *(const f32x4*)(b + cc);
    bf16x4 s4 = *(const bf16x4*)(sr + (size_t)row * CC + cc);
    bf16x4 o;
#pragma unroll
    for (int j = 0; j < 4; ++j)
      o[j] = (bf16_t)(((x[s * 4 + j] - mean) * rs * gg[j] + bb[j]) * (float)s4[j]);
    *(bf16x4*)(out + (size_t)row * CC + cc) = o;
  }
}

// ---------------- LN over HID=3072 bf16 rows, IN-PLACE ----------------
// Each wave owns a full row: loads all 48 elems/lane first, stats, then
// overwrites the same row. In-place is safe (no cross-row deps) and frees
// the KFb buffer (8 B/elem of workspace) -> CB=128 single-chunk fits.
__global__ __launch_bounds__(256) void k_ln_hid(bf16_t* __restrict__ io,
                                                const float* __restrict__ g,
                                                const float* __restrict__ b, int M) {
  int row = blockIdx.x * 4 + (threadIdx.x >> 6);
  if (row >= M) return;
  int lane = threadIdx.x & 63;
  bf16_t* rp = io + (size_t)row * HD;
  int c0 = lane * 8;
  bf16x8 x[6];
#pragma unroll
  for (int s = 0; s < 6; ++s) x[s] = *(const bf16x8*)(rp + s * 512 + c0);
  float sum = 0.f;
#pragma unroll
  for (int s = 0; s < 6; ++s)
#pragma unroll
    for (int j = 0; j < 8; ++j) sum += (float)x[s][j];
  float mean = wave_sum(sum) * (1.0f / HD);
  float s2 = 0.f;
#pragma unroll
  for (int s = 0; s < 6; ++s)
#pragma unroll
    for (int j = 0; j < 8; ++j) { float d = (float)x[s][j] - mean; s2 += d * d; }
  float rs = rsqrtf(wave_sum(s2) * (1.0f / HD) + EPSF);
#pragma unroll
  for (int s = 0; s < 6; ++s) {
    int cc = s * 512 + c0;
    f32x4 g0 = *(const f32x4*)(g + cc);
    f32x4 g1 = *(const f32x4*)(g + cc + 4);
    f32x4 b0 = *(const f32x4*)(b + cc);
    f32x4 b1 = *(const f32x4*)(b + cc + 4);
    bf16x8 o;
#pragma unroll
    for (int j = 0; j < 4; ++j) {
      o[j]     = (bf16_t)(((float)x[s][j]     - mean) * rs * g0[j] + b0[j]);
      o[j + 4] = (bf16_t)(((float)x[s][j + 4] - mean) * rs * g1[j] + b1[j]);
    }
    *(bf16x8*)(rp + cc) = o;
  }
}

// ---------------- host orchestration ----------------
// Workspace plan (B/elem of MC):
//   big(10): [K32(4)|V32(4)|SR16(2)]  vs  [KFa(8) in-place LN | (SR16 slot free)]
//   a16/b16/c16(2 each): xk/xv/xr -> then P16/Q16/R16 (dead-window reuse)
// Total 16 B/elem (was 22) -> CB=128 ~ 323 MB incl. weights.
struct Layout {
  size_t wk, wv, wr, wo, fk, fv, fr;
  size_t st, big, a16, b16, c16;
  size_t end;
};

static Layout make_layout(int CB) {
  Layout L;
  size_t off = 0;
  auto al = [&](size_t bytes) { size_t o = (off + 255) & ~(size_t)255; off = o + bytes; return o; };
  L.wk = al(589824ull * 2);
  L.wv = al(589824ull * 2);
  L.wr = al(589824ull * 2);
  L.wo = al(589824ull * 2);
  L.fk = al(2359296ull * 2);
  L.fv = al(2359296ull * 2);
  L.fr = al(589824ull * 2);
  size_t M = (size_t)CB * 196;
  size_t MC = M * 768;
  L.st  = al(M * 8);
  L.big = al(MC * 10);   // union: [K32|V32|SR16] vs [KFa]
  L.a16 = al(MC * 2);
  L.b16 = al(MC * 2);
  L.c16 = al(MC * 2);
  L.end = off;
  return L;
}

extern "C" void kernel_launch(void* const* d_in, const int* in_sizes, int n_in,
                              void* d_out, int out_size, void* d_ws, size_t ws_size,
                              hipStream_t stream) {
  const float* x      = (const float*)d_in[0];
  const float* ln0_g  = (const float*)d_in[1];
  const float* ln0_b  = (const float*)d_in[2];
  const float* ln1_g  = (const float*)d_in[3];
  const float* ln1_b  = (const float*)d_in[4];
  const float* ln2_g  = (const float*)d_in[5];
  const float* ln2_b  = (const float*)d_in[6];
  const float* amk    = (const float*)d_in[7];
  const float* amv    = (const float*)d_in[8];
  const float* amr    = (const float*)d_in[9];
  const float* adec   = (const float*)d_in[10];
  const float* afirst = (const float*)d_in[11];
  const float* aWk    = (const float*)d_in[12];
  const float* aWv    = (const float*)d_in[13];
  const float* aWr    = (const float*)d_in[14];
  const float* aWo    = (const float*)d_in[15];
  const float* akn_g  = (const float*)d_in[16];
  const float* akn_b  = (const float*)d_in[17];
  const float* fmk    = (const float*)d_in[18];
  const float* fmr    = (const float*)d_in[19];
  const float* fWk    = (const float*)d_in[20];
  const float* fWv    = (const float*)d_in[21];
  const float* fWr    = (const float*)d_in[22];
  const float* fkn_g  = (const float*)d_in[23];
  const float* fkn_b  = (const float*)d_in[24];

  int CB = 32;
  {
    const int cands[3] = {128, 64, 32};
    for (int i = 0; i < 3; ++i)
      if (make_layout(cands[i]).end <= ws_size) { CB = cands[i]; break; }
  }
  Layout L = make_layout(CB);
  int nchunk = 128 / CB;
  int M = CB * 196;
  size_t MC = (size_t)M * 768;

  uint8_t* ws = (uint8_t*)d_ws;
  bf16_t* WkT = (bf16_t*)(ws + L.wk);
  bf16_t* WvT = (bf16_t*)(ws + L.wv);
  bf16_t* WrT = (bf16_t*)(ws + L.wr);
  bf16_t* WoT = (bf16_t*)(ws + L.wo);
  bf16_t* FkT = (bf16_t*)(ws + L.fk);
  bf16_t* FvT = (bf16_t*)(ws + L.fv);
  bf16_t* FrT = (bf16_t*)(ws + L.fr);
  float*  ST  = (float*)(ws + L.st);
  uint8_t* big = ws + L.big;
  float*  K32 = (float*)(big);
  float*  V32 = (float*)(big + MC * 4);
  bf16_t* SR16 = (bf16_t*)(big + MC * 8);
  bf16_t* KFa = (bf16_t*)(big);            // M x 3072 bf16 (aliases K32+V32, dead by then)
  bf16_t* A16 = (bf16_t*)(ws + L.a16);
  bf16_t* B16 = (bf16_t*)(ws + L.b16);
  bf16_t* C16 = (bf16_t*)(ws + L.c16);
  // dead-window aliases: P/Q/R live in the xk/xv/xr buffers (consumed by QKV gemm)
  bf16_t* P16 = A16;
  bf16_t* Q16 = B16;
  bf16_t* R16 = C16;

  {
    TcvtBatch tb;
    tb.p[0] = {aWk, WkT}; tb.p[1] = {aWv, WvT}; tb.p[2] = {aWr, WrT};
    tb.p[3] = {aWo, WoT}; tb.p[4] = {fWr, FrT};
    k_tcvt5<<<dim3(24, 24, 5), 256, 0, stream>>>(tb);
  }
  k_tcvt<<<dim3(96, 24), 256, 0, stream>>>(fWk, FkT, 768, 3072);
  k_tcvt<<<dim3(24, 96), 256, 0, stream>>>(fWv, FvT, 3072, 768);

  int rowb = M / 4;
  int Mt = M / 128;
  int wkvb = (CB * 768) / 256;

  for (int ch = 0; ch < nchunk; ++ch) {
    const float* xin = x + (size_t)ch * MC;
    float* XB = (float*)d_out + (size_t)ch * MC;   // residual stream lives in d_out

    // ---- attention half ----
    k_ln0<<<rowb, 256, 0, stream>>>(xin, ln0_g, ln0_b, XB, ST, M);
    k_mix<3><<<rowb, 256, 0, stream>>>(XB, ST, ln1_g, ln1_b, amk, amv, amr, A16, B16, C16, M);
    {
      GemmBatch gb{};
      gb.a[0] = {A16, WkT, K32, nullptr, nullptr, EPI_F32, 6};
      gb.a[1] = {B16, WvT, V32, nullptr, nullptr, EPI_F32, 6};
      gb.a[2] = {C16, WrT, SR16, nullptr, nullptr, EPI_SIG_BF16, 6};
      k_gemm<<<dim3(Mt * 18), 256, 0, stream>>>(gb, M, 768, Mt);
    }
    // A16/B16/C16 (xk/xv/xr) are dead now -> reuse as P16/Q16/R16
    k_wkv_bwd<<<wkvb, 256, 0, stream>>>(K32, V32, adec, P16, Q16, CB);
    k_wkv_fwd<<<wkvb, 256, 0, stream>>>(K32, V32, adec, afirst, P16, Q16, R16, CB);
    // ln_mul reads R16(=C16) + SR16, writes A16 (P16 dead after fwd)
    k_ln_mul<<<rowb, 256, 0, stream>>>(R16, SR16, akn_g, akn_b, A16, M);
    {
      GemmBatch gb{};
      gb.a[0] = {A16, WoT, XB, nullptr, nullptr, EPI_ADD, 6};
      k_gemm<<<dim3(Mt * 6), 256, 0, stream>>>(gb, M, 768, Mt);
    }

    // ---- ffn half ----
    k_stats<<<rowb, 256, 0, stream>>>(XB, ST, M);
    k_mix<2><<<rowb, 256, 0, stream>>>(XB, ST, ln2_g, ln2_b, fmk, nullptr, fmr, A16, nullptr, C16, M);
    {
      // FFN-K (NT=24) and Wr (NT=6) are independent: fuse into one launch
      // KFa aliases K32/V32 (dead); SR16 slot is NOT part of KFa (no overlap)
      GemmBatch gb{};
      gb.a[0] = {A16, FkT, KFa, nullptr, nullptr, EPI_RELU2_BF16, 24};
      gb.a[1] = {C16, FrT, B16, nullptr, nullptr, EPI_SIG_BF16, 6};
      k_gemm<<<dim3(Mt * 30), 256, 0, stream>>>(gb, M, 768, Mt);
    }
    k_ln_hid<<<rowb, 256, 0, stream>>>(KFa, fkn_g, fkn_b, M);   // in-place
    {
      GemmBatch gb{};
      gb.a[0] = {KFa, FvT, XB, B16, XB, EPI_GATE, 6};
      k_gemm<<<dim3(Mt * 6), 256, 0, stream>>>(gb, M, 3072, Mt);
    }
  }
}